// Round 19
// baseline (106.311 us; speedup 1.0000x reference)
//
#include <hip/hip_runtime.h>
#include <cfloat>
#include <math.h>

#define SB 1024   // sequence length S = H*W
#define CC 512    // channels
#define NB 8      // batch
#define NH 8      // heads
#define HD 64     // head dim

typedef short short8 __attribute__((ext_vector_type(8)));
typedef short s16x4 __attribute__((ext_vector_type(4)));
typedef float f32x4 __attribute__((ext_vector_type(4)));

__device__ __forceinline__ short f2bs(float f) {
    union { float f; unsigned u; } x; x.f = f;
    unsigned r = x.u + 0x7fffu + ((x.u >> 16) & 1u);   // RNE to bf16
    return (short)(r >> 16);
}

// pack two f32 -> one dword of 2 bf16 (RNE), gfx950 HW op (T12 primitive)
__device__ __forceinline__ int cvtpk(float lo, float hi) {
    int r;
    asm("v_cvt_pk_bf16_f32 %0, %1, %2" : "=v"(r) : "v"(lo), "v"(hi));
    return r;
}

__device__ __forceinline__ void gload16(const void* g, void* l) {
    __builtin_amdgcn_global_load_lds(
        (const __attribute__((address_space(1))) unsigned int*)g,
        (__attribute__((address_space(3))) unsigned int*)l, 16, 0, 0);
}

// swizzled short-index within a [rows][64-short] LDS tile (128B rows)
__device__ __forceinline__ int sidx(int row, int colb) {
    return row * 64 + ((colb ^ ((row & 7) << 4)) >> 1);
}

// ---------------------------------------------------------------------------
// prep: fused auxiliary pass.
//   blocks [0,1024):    weights fp32 -> bf16
//   blocks [1024,2048): x (B,C,S) fp32 -> xT (B,S,C) bf16 (tile transpose)
//   blocks [2048,2080): mask -> float 0/-FLT_MAX
//   blocks [2080,2096): zero vmean accumulator (gemm_qkv atomically adds)
// ---------------------------------------------------------------------------
__global__ __launch_bounds__(256)
void prep(const float* __restrict__ w1, const float* __restrict__ w2,
          short* __restrict__ o1, short* __restrict__ o2,
          const float* __restrict__ x, short* __restrict__ xT,
          const int* __restrict__ mask, float* __restrict__ maskf,
          float* __restrict__ vmean)
{
    const int B = blockIdx.x;
    const int tid = threadIdx.x;
    if (B < 1024) {
        const int i4 = B * 256 + tid;
        const int N1 = 1536 * 512 / 4;
        if (i4 < N1) {
            float4 v = *(const float4*)&w1[(size_t)i4 * 4];
            s16x4 p; p[0] = f2bs(v.x); p[1] = f2bs(v.y); p[2] = f2bs(v.z); p[3] = f2bs(v.w);
            *(s16x4*)&o1[(size_t)i4 * 4] = p;
        } else {
            const int j = i4 - N1;
            float4 v = *(const float4*)&w2[(size_t)j * 4];
            s16x4 p; p[0] = f2bs(v.x); p[1] = f2bs(v.y); p[2] = f2bs(v.z); p[3] = f2bs(v.w);
            *(s16x4*)&o2[(size_t)j * 4] = p;
        }
    } else if (B < 2048) {
        const int idx = B - 1024;
        const int bs = idx & 15, bc = (idx >> 4) & 7, b = idx >> 7;
        __shared__ short T[64][72];
        {
            const int cl = tid >> 4;
            const int s4 = (tid & 15) * 4;
            #pragma unroll
            for (int r = 0; r < 4; ++r) {
                const int c = cl + 16 * r;
                float4 v = *(const float4*)&x[((size_t)b * CC + bc * 64 + c) * SB + bs * 64 + s4];
                T[s4 + 0][c] = f2bs(v.x); T[s4 + 1][c] = f2bs(v.y);
                T[s4 + 2][c] = f2bs(v.z); T[s4 + 3][c] = f2bs(v.w);
            }
        }
        __syncthreads();
        {
            const int sl = tid >> 2;
            const int c16 = (tid & 3) * 16;
            short8 v0 = *(const short8*)&T[sl][c16];
            short8 v1 = *(const short8*)&T[sl][c16 + 8];
            short* dst = &xT[((size_t)b * SB + bs * 64 + sl) * CC + bc * 64 + c16];
            *(short8*)&dst[0] = v0;
            *(short8*)&dst[8] = v1;
        }
    } else if (B < 2080) {
        const int gi = (B - 2048) * 256 + tid;
        if (gi < NB * SB) maskf[gi] = (mask[gi] != 0) ? -FLT_MAX : 0.f;
    } else {
        const int i = (B - 2080) * 256 + tid;
        if (i < NB * CC) vmean[i] = 0.f;
    }
}

// ---------------------------------------------------------------------------
// qkv GEMM (R15): 64(o) x 128(s) tile, grid (8,24,8) = 1536 blocks ->
// 6 blocks/CU = 24 waves/CU. LDS 24 KB. One head per o-tile for q/k.
// o<512 -> qT[b,h,s,d] * (0.125*log2e); o<1024 -> kT[b,h,s,d];
// else v[b,c,s] + fp32 atomic partial sums into vmean[b][c] (raw sums).
// ---------------------------------------------------------------------------
__global__ __launch_bounds__(256)
void gemm_qkv(const short* __restrict__ A, const float* __restrict__ bias,
              const short* __restrict__ BT,
              short* __restrict__ qTo, short* __restrict__ kTo,
              short* __restrict__ vo, float* __restrict__ vmean)
{
    const int bs = blockIdx.x;   // s-tile (8)
    const int bo = blockIdx.y;   // o-tile (24)
    const int b  = blockIdx.z;
    const int tid = threadIdx.x;
    const int wave = tid >> 6, lane = tid & 63, lg = lane >> 4, ln = lane & 15;
    const int wo = wave >> 1, ws = wave & 1;

    __shared__ short Al[64 * 64];    //  8 KB
    __shared__ short Bl[128 * 64];   // 16 KB

    f32x4 acc[2][4];
    #pragma unroll
    for (int mt = 0; mt < 2; ++mt)
        #pragma unroll
        for (int nt = 0; nt < 4; ++nt) acc[mt][nt] = (f32x4){0.f, 0.f, 0.f, 0.f};

    const char* Ab = (const char*)(A + (size_t)bo * 64 * 512);
    const char* Bb = (const char*)(BT + ((size_t)b * SB + bs * 128) * 512);

    for (int kc = 0; kc < 512; kc += 64) {
        __syncthreads();
        #pragma unroll
        for (int sw = 0; sw < 2; ++sw) {     // A: 8KB
            const int lin = tid * 16 + sw * 4096;
            const int row = lin >> 7;         // 0..63
            const int scol = (lin & 127) ^ ((row & 7) << 4);
            gload16(Ab + ((size_t)row * 512 + kc) * 2 + scol,
                    (char*)Al + (wave << 10) + (sw << 12));
        }
        #pragma unroll
        for (int sw = 0; sw < 4; ++sw) {     // B: 16KB
            const int lin = tid * 16 + sw * 4096;
            const int row = lin >> 7;         // 0..127
            const int scol = (lin & 127) ^ ((row & 7) << 4);
            gload16(Bb + ((size_t)row * 512 + kc) * 2 + scol,
                    (char*)Bl + (wave << 10) + (sw << 12));
        }
        __syncthreads();
        #pragma unroll
        for (int kk = 0; kk < 2; ++kk) {
            const int colb = kk * 64 + lg * 16;
            short8 a[2], bb[4];
            #pragma unroll
            for (int mt = 0; mt < 2; ++mt)
                a[mt] = *(const short8*)&Al[sidx(wo * 32 + mt * 16 + ln, colb)];
            #pragma unroll
            for (int nt = 0; nt < 4; ++nt)
                bb[nt] = *(const short8*)&Bl[sidx(ws * 64 + nt * 16 + ln, colb)];
            #pragma unroll
            for (int mt = 0; mt < 2; ++mt)
                #pragma unroll
                for (int nt = 0; nt < 4; ++nt)
                    acc[mt][nt] = __builtin_amdgcn_mfma_f32_16x16x32_bf16(
                        a[mt], bb[nt], acc[mt][nt], 0, 0, 0);
        }
    }

    if (bo < 16) {   // q or k -> transposed [b,h,s,d]; one head per block
        short* dst = (bo < 8) ? qTo : kTo;
        const int h = bo & 7;
        const float sc = (bo < 8) ? 0.18033688011112042f : 1.0f;  // 0.125*log2(e)
        #pragma unroll
        for (int mt = 0; mt < 2; ++mt) {
            const int d0 = wo * 32 + mt * 16 + 4 * lg;
            const int o0 = bo * 64 + d0;
            const float b0 = bias[o0], b1 = bias[o0 + 1],
                        b2 = bias[o0 + 2], b3 = bias[o0 + 3];
            #pragma unroll
            for (int nt = 0; nt < 4; ++nt) {
                const int s = bs * 128 + ws * 64 + nt * 16 + ln;
                s16x4 pk;
                pk[0] = f2bs((acc[mt][nt][0] + b0) * sc);
                pk[1] = f2bs((acc[mt][nt][1] + b1) * sc);
                pk[2] = f2bs((acc[mt][nt][2] + b2) * sc);
                pk[3] = f2bs((acc[mt][nt][3] + b3) * sc);
                *(s16x4*)&dst[(((size_t)b * NH + h) * SB + s) * HD + d0] = pk;
            }
        }
    } else {        // v -> natural [b,c,s] + vmean partial sums
        #pragma unroll
        for (int mt = 0; mt < 2; ++mt) {
            const int cv0 = (bo - 16) * 64 + wo * 32 + mt * 16 + 4 * lg;
            #pragma unroll
            for (int r = 0; r < 4; ++r) {
                const float bv = bias[1024 + cv0 + r];
                float part = 0.f;
                #pragma unroll
                for (int nt = 0; nt < 4; ++nt) {
                    const int s = bs * 128 + ws * 64 + nt * 16 + ln;
                    const float val = acc[mt][nt][r] + bv;
                    part += val;
                    vo[((size_t)b * CC + cv0 + r) * SB + s] = f2bs(val);
                }
                #pragma unroll
                for (int o = 1; o < 16; o <<= 1)
                    part += __shfl_xor(part, o, 64);
                if (ln == 0)
                    atomicAdd(&vmean[(size_t)b * CC + cv0 + r], part);
            }
        }
    }
}

// ---------------------------------------------------------------------------
// proj GEMM (R16): 64(o) x 64(s) tile, grid (16,8,8) = 1024 blocks ->
// 4 blocks/CU = 16 waves/CU. LDS 16 KB. fp32 out [b,o,s].
// ---------------------------------------------------------------------------
__global__ __launch_bounds__(256)
void gemm_proj(const short* __restrict__ A, const float* __restrict__ bias,
               const short* __restrict__ BT, float* __restrict__ fo)
{
    const int bs = blockIdx.x;   // s-tile (16)
    const int bo = blockIdx.y;   // o-tile (8)
    const int b  = blockIdx.z;
    const int tid = threadIdx.x;
    const int wave = tid >> 6, lane = tid & 63, lg = lane >> 4, ln = lane & 15;
    const int wo = wave >> 1, ws = wave & 1;

    __shared__ short Al[64 * 64];    //  8 KB
    __shared__ short Bl[64 * 64];    //  8 KB

    f32x4 acc[2][2];
    #pragma unroll
    for (int mt = 0; mt < 2; ++mt)
        #pragma unroll
        for (int nt = 0; nt < 2; ++nt) acc[mt][nt] = (f32x4){0.f, 0.f, 0.f, 0.f};

    const char* Ab = (const char*)(A + (size_t)bo * 64 * 512);
    const char* Bb = (const char*)(BT + ((size_t)b * SB + bs * 64) * 512);

    for (int kc = 0; kc < 512; kc += 64) {
        __syncthreads();
        #pragma unroll
        for (int sw = 0; sw < 2; ++sw) {
            const int lin = tid * 16 + sw * 4096;
            const int row = lin >> 7;         // 0..63
            const int scol = (lin & 127) ^ ((row & 7) << 4);
            gload16(Ab + ((size_t)row * 512 + kc) * 2 + scol,
                    (char*)Al + (wave << 10) + (sw << 12));
            gload16(Bb + ((size_t)row * 512 + kc) * 2 + scol,
                    (char*)Bl + (wave << 10) + (sw << 12));
        }
        __syncthreads();
        #pragma unroll
        for (int kk = 0; kk < 2; ++kk) {
            const int colb = kk * 64 + lg * 16;
            short8 a[2], bb[2];
            #pragma unroll
            for (int mt = 0; mt < 2; ++mt)
                a[mt] = *(const short8*)&Al[sidx(wo * 32 + mt * 16 + ln, colb)];
            #pragma unroll
            for (int nt = 0; nt < 2; ++nt)
                bb[nt] = *(const short8*)&Bl[sidx(ws * 32 + nt * 16 + ln, colb)];
            #pragma unroll
            for (int mt = 0; mt < 2; ++mt)
                #pragma unroll
                for (int nt = 0; nt < 2; ++nt)
                    acc[mt][nt] = __builtin_amdgcn_mfma_f32_16x16x32_bf16(
                        a[mt], bb[nt], acc[mt][nt], 0, 0, 0);
        }
    }

    #pragma unroll
    for (int mt = 0; mt < 2; ++mt) {
        #pragma unroll
        for (int r = 0; r < 4; ++r) {
            const int o = bo * 64 + wo * 32 + mt * 16 + 4 * lg + r;
            const float bv = bias[o];
            #pragma unroll
            for (int nt = 0; nt < 2; ++nt) {
                const int s = bs * 64 + ws * 32 + nt * 16 + ln;
                fo[((size_t)b * CC + o) * SB + s] = acc[mt][nt][r] + bv;
            }
        }
    }
}

// ---------------------------------------------------------------------------
// Double-buffered MFMA attention (R18 base) + V direct-to-register:
//  - V's PV A-fragment is a contiguous 16B/lane read from vN[b,c,s] -- no
//    transpose needed, so LDS staging of V only bought latency hiding,
//    which early issue (T14) provides for free. V frags loaded to registers
//    right after the mask loads (~600 cy before use); Vs LDS buffer GONE.
//  - Staging gload16s/tile halve (4->2); barrier vmcnt drain halves;
//    8 ds_read_b128/tile become L1/L2-hot global loads (8 blocks per bh
//    share V tiles on one XCD). LDS 40960 -> 24576 B.
//  - launch_bounds (256,4) keeps VGPR cap 128 (R7 lesson); WRITE_SIZE is
//    the spill tripwire.
//  - Rest identical to R18 (speculative softmax, cvt_pk, deferred l-reduce,
//    setprio, defer-max, exp2 domain, Ps XOR-swizzle, vmean for dead rows).
// ---------------------------------------------------------------------------
__global__ __launch_bounds__(256, 4)
void attn_mfma(const short* __restrict__ qT, const short* __restrict__ kT,
               const short* __restrict__ vN, const float* __restrict__ maskf,
               const float* __restrict__ vmean, short* __restrict__ ctxT)
{
    const int L  = blockIdx.x;
    const int qb = 15 - (L >> 6);         // heavy blocks first
    const int bh = L & 63;                // XCD = L%8 = h -> per-(b,h) L2 reuse
    const int b  = bh >> 3, h = bh & 7;
    const int tid = threadIdx.x;
    const int wave = tid >> 6;
    const int lane = tid & 63;
    const int lg = lane >> 4;
    const int ln = lane & 15;

    __shared__ short Ks[2][64 * 64];      // 16384 B
    __shared__ short Ps[4][16 * 64];      //  8192 B   (total 24576 B)

    const char*  kbh = (const char*)(kT + (((size_t)b * NH + h) * SB) * HD);
    const short* vbh = vN + ((size_t)b * CC + h * HD) * SB;   // [d][t]
    const float* mb  = maskf + (size_t)b * SB;

    short8 qa0, qa1;
    {
        const short* qrow = qT + (((size_t)b * NH + h) * SB + qb * 64 + wave * 16 + ln) * HD;
        qa0 = *(const short8*)&qrow[8 * lg];
        qa1 = *(const short8*)&qrow[32 + 8 * lg];
    }

    const int psw = (ln & 7) << 3;        // per-row Ps XOR constant

    float m_ = -FLT_MAX, l_ = 0.f;        // l_ is a PER-LANE partial
    f32x4 acc[4];
    #pragma unroll
    for (int nt = 0; nt < 4; ++nt) acc[nt] = (f32x4){0.f, 0.f, 0.f, 0.f};

    auto stage = [&](int tb, int bi) {    // K only: 2 x 4KB via gload16
        #pragma unroll
        for (int sw = 0; sw < 2; ++sw) {
            const int lin = tid * 16 + sw * 4096;
            const int row = lin >> 7;
            const int scol = (lin & 127) ^ ((row & 7) << 4);
            gload16(kbh + (size_t)tb * 128 + row * 128 + scol,
                    (char*)&Ks[bi][0] + (wave << 10) + (sw << 12));
        }
    };

    int cur = 0;
    stage(0, 0);
    __syncthreads();

    for (int t = 0; t <= qb; ++t) {
        const int tb = t * 64;

        // ---- mask + V-fragment loads issued FIRST (hide under QK^T) ----
        float4 mf[4];
        #pragma unroll
        for (int nt = 0; nt < 4; ++nt)
            mf[nt] = *(const float4*)&mb[tb + 16 * nt + 4 * lg];
        short8 va0[4], va1[4];
        #pragma unroll
        for (int nt = 0; nt < 4; ++nt) {
            const short* vr = vbh + (size_t)(16 * nt + ln) * SB + tb;
            va0[nt] = *(const short8*)&vr[8 * lg];
            va1[nt] = *(const short8*)&vr[32 + 8 * lg];
        }

        if (t < qb) stage((t + 1) * 64, cur ^ 1);

        // ---- swapped QK^T: sc[nt][r] = S[q=ln][key 16nt+4lg+r] ----
        f32x4 sc[4];
        __builtin_amdgcn_s_setprio(1);
        #pragma unroll
        for (int nt = 0; nt < 4; ++nt) {
            short8 kb0 = *(const short8*)&Ks[cur][sidx(ln + 16 * nt, lg * 16)];
            short8 kb1 = *(const short8*)&Ks[cur][sidx(ln + 16 * nt, 64 + lg * 16)];
            f32x4 z = (f32x4){0.f, 0.f, 0.f, 0.f};
            z = __builtin_amdgcn_mfma_f32_16x16x32_bf16(kb0, qa0, z, 0, 0, 0);
            z = __builtin_amdgcn_mfma_f32_16x16x32_bf16(kb1, qa1, z, 0, 0, 0);
            sc[nt] = z;
        }
        __builtin_amdgcn_s_setprio(0);

        #pragma unroll
        for (int nt = 0; nt < 4; ++nt) {
            sc[nt][0] += mf[nt].x; sc[nt][1] += mf[nt].y;
            sc[nt][2] += mf[nt].z; sc[nt][3] += mf[nt].w;
        }
        if (t == qb) {
            const int so = wave * 16 + ln;
            #pragma unroll
            for (int nt = 0; nt < 4; ++nt)
                #pragma unroll
                for (int r = 0; r < 4; ++r)
                    if (16 * nt + 4 * lg + r > so) sc[nt][r] = -FLT_MAX;
        }

        // ---- owner-lane in-register max, cross-lane reduce in flight ----
        float mx = sc[0][0];
        #pragma unroll
        for (int nt = 0; nt < 4; ++nt)
            #pragma unroll
            for (int r = 0; r < 4; ++r)
                if (nt | r) mx = fmaxf(mx, sc[nt][r]);
        float mxr = fmaxf(mx, __shfl_xor(mx, 16, 64));
        mxr = fmaxf(mxr, __shfl_xor(mxr, 32, 64));

        // ---- speculative P with STALE m_ (overlaps the shuffles) ----
        float rs = 0.f;
        int2 pkw[4];
        #pragma unroll
        for (int nt = 0; nt < 4; ++nt) {
            float p0 = exp2f(sc[nt][0] - m_);
            float p1 = exp2f(sc[nt][1] - m_);
            float p2 = exp2f(sc[nt][2] - m_);
            float p3 = exp2f(sc[nt][3] - m_);
            rs += (p0 + p1) + (p2 + p3);
            pkw[nt].x = cvtpk(p0, p1);
            pkw[nt].y = cvtpk(p2, p3);
        }

        // ---- rare path: some query's max grew beyond threshold ----
        if (!__all(mxr <= m_ + 11.5f)) {
            const float mnew = fmaxf(m_, mxr);
            const float fq = exp2f(m_ - mnew);   // 0-0 -> 1 (all-masked rows)
            l_ *= fq;
            #pragma unroll
            for (int nt = 0; nt < 4; ++nt)
                #pragma unroll
                for (int r = 0; r < 4; ++r) acc[nt][r] *= fq;
            m_ = mnew;
            rs = 0.f;
            #pragma unroll
            for (int nt = 0; nt < 4; ++nt) {
                float p0 = exp2f(sc[nt][0] - m_);
                float p1 = exp2f(sc[nt][1] - m_);
                float p2 = exp2f(sc[nt][2] - m_);
                float p3 = exp2f(sc[nt][3] - m_);
                rs += (p0 + p1) + (p2 + p3);
                pkw[nt].x = cvtpk(p0, p1);
                pkw[nt].y = cvtpk(p2, p3);
            }
        }

        // ---- commit P; l_ stays a per-lane partial (merged in epilogue) ----
        #pragma unroll
        for (int nt = 0; nt < 4; ++nt)
            *(int2*)&Ps[wave][ln * 64 + ((16 * nt + 4 * lg) ^ psw)] = pkw[nt];
        l_ += rs;

        // ---- PV as mfma(V, P) with register V frags ----
        const short8 pa0 = *(const short8*)&Ps[wave][ln * 64 + ((8 * lg) ^ psw)];
        const short8 pa1 = *(const short8*)&Ps[wave][ln * 64 + ((32 + 8 * lg) ^ psw)];
        __builtin_amdgcn_s_setprio(1);
        #pragma unroll
        for (int nt = 0; nt < 4; ++nt) {
            acc[nt] = __builtin_amdgcn_mfma_f32_16x16x32_bf16(va0[nt], pa0, acc[nt], 0, 0, 0);
            acc[nt] = __builtin_amdgcn_mfma_f32_16x16x32_bf16(va1[nt], pa1, acc[nt], 0, 0, 0);
        }
        __builtin_amdgcn_s_setprio(0);

        if (t < qb) {
            __syncthreads();
            cur ^= 1;
        }
    }

    // ---- epilogue: merge per-lane l partials (2 shfl), normalize, store ----
    float lt = l_ + __shfl_xor(l_, 16, 64);
    lt += __shfl_xor(lt, 32, 64);
    const float rl = 1.f / lt;
    const bool dead = (m_ == -FLT_MAX);
    const float* vmb = vmean + (size_t)b * CC + h * HD;
    const int s = qb * 64 + wave * 16 + ln;
    short* crow = ctxT + ((size_t)b * SB + s) * CC + h * HD;
    #pragma unroll
    for (int nt = 0; nt < 4; ++nt) {
        const int d0 = 16 * nt + 4 * lg;
        const float4 vm4 = *(const float4*)&vmb[d0];
        const float v0 = dead ? vm4.x * (1.f / 1024.f) : acc[nt][0] * rl;
        const float v1 = dead ? vm4.y * (1.f / 1024.f) : acc[nt][1] * rl;
        const float v2 = dead ? vm4.z * (1.f / 1024.f) : acc[nt][2] * rl;
        const float v3 = dead ? vm4.w * (1.f / 1024.f) : acc[nt][3] * rl;
        int2 w;
        w.x = cvtpk(v0, v1);
        w.y = cvtpk(v2, v3);
        *(int2*)&crow[d0] = w;
    }
}

extern "C" void kernel_launch(void* const* d_in, const int* in_sizes, int n_in,
                              void* d_out, int out_size, void* d_ws, size_t ws_size,
                              hipStream_t stream) {
    const float* x      = (const float*)d_in[0];
    const int*   amask  = (const int*)d_in[1];
    const float* qkv_w  = (const float*)d_in[2];
    const float* qkv_b  = (const float*)d_in[3];
    const float* proj_w = (const float*)d_in[4];
    const float* proj_b = (const float*)d_in[5];
    float* out = (float*)d_out;

    short* xT    = (short*)d_ws;                       // (B,S,C)
    short* w1b   = xT  + (size_t)NB * SB * CC;         // (1536,512)
    short* w2b   = w1b + (size_t)1536 * 512;           // (512,512)
    short* qT    = w2b + (size_t)512 * 512;            // (B,H,S,D)
    short* kT    = qT  + (size_t)NB * NH * SB * HD;    // (B,H,S,D)
    short* vN    = kT  + (size_t)NB * NH * SB * HD;    // (B,C,S)
    short* ctxT  = vN  + (size_t)NB * CC * SB;         // (B,S,C)
    float* vmean = (float*)(ctxT + (size_t)NB * SB * CC);  // (B,C) raw sums
    float* maskf = vmean + (size_t)NB * CC;            // (B,S)

    prep<<<2096, 256, 0, stream>>>(qkv_w, proj_w, w1b, w2b, x, xT,
                                   amask, maskf, vmean);
    gemm_qkv<<<dim3(8, 24, NB), 256, 0, stream>>>(
        w1b, qkv_b, xT, qT, kT, vN, vmean);
    attn_mfma<<<dim3(1024, 1, 1), 256, 0, stream>>>(qT, kT, vN, maskf, vmean, ctxT);
    gemm_proj<<<dim3(16, 8, NB), 256, 0, stream>>>(
        w2b, proj_b, ctxT, out);
}

// Round 20
// 74.232 us; speedup vs baseline: 1.4321x; 1.4321x over previous
//
#include <hip/hip_runtime.h>
#include <cfloat>
#include <math.h>

#define SB 1024   // sequence length S = H*W
#define CC 512    // channels
#define NB 8      // batch
#define NH 8      // heads
#define HD 64     // head dim

typedef short short8 __attribute__((ext_vector_type(8)));
typedef short s16x4 __attribute__((ext_vector_type(4)));
typedef float f32x4 __attribute__((ext_vector_type(4)));

__device__ __forceinline__ short f2bs(float f) {
    union { float f; unsigned u; } x; x.f = f;
    unsigned r = x.u + 0x7fffu + ((x.u >> 16) & 1u);   // RNE to bf16
    return (short)(r >> 16);
}

// pack two f32 -> one dword of 2 bf16 (RNE), gfx950 HW op (T12 primitive)
__device__ __forceinline__ int cvtpk(float lo, float hi) {
    int r;
    asm("v_cvt_pk_bf16_f32 %0, %1, %2" : "=v"(r) : "v"(lo), "v"(hi));
    return r;
}

__device__ __forceinline__ void gload16(const void* g, void* l) {
    __builtin_amdgcn_global_load_lds(
        (const __attribute__((address_space(1))) unsigned int*)g,
        (__attribute__((address_space(3))) unsigned int*)l, 16, 0, 0);
}

// swizzled short-index within a [rows][64-short] LDS tile (128B rows)
__device__ __forceinline__ int sidx(int row, int colb) {
    return row * 64 + ((colb ^ ((row & 7) << 4)) >> 1);
}

// ---------------------------------------------------------------------------
// prep: fused auxiliary pass.
//   blocks [0,1024):    weights fp32 -> bf16
//   blocks [1024,2048): x (B,C,S) fp32 -> xT (B,S,C) bf16 (tile transpose)
//   blocks [2048,2080): mask -> float 0/-FLT_MAX
//   blocks [2080,2096): zero vmean accumulator (gemm_qkv atomically adds)
// ---------------------------------------------------------------------------
__global__ __launch_bounds__(256)
void prep(const float* __restrict__ w1, const float* __restrict__ w2,
          short* __restrict__ o1, short* __restrict__ o2,
          const float* __restrict__ x, short* __restrict__ xT,
          const int* __restrict__ mask, float* __restrict__ maskf,
          float* __restrict__ vmean)
{
    const int B = blockIdx.x;
    const int tid = threadIdx.x;
    if (B < 1024) {
        const int i4 = B * 256 + tid;
        const int N1 = 1536 * 512 / 4;
        if (i4 < N1) {
            float4 v = *(const float4*)&w1[(size_t)i4 * 4];
            s16x4 p; p[0] = f2bs(v.x); p[1] = f2bs(v.y); p[2] = f2bs(v.z); p[3] = f2bs(v.w);
            *(s16x4*)&o1[(size_t)i4 * 4] = p;
        } else {
            const int j = i4 - N1;
            float4 v = *(const float4*)&w2[(size_t)j * 4];
            s16x4 p; p[0] = f2bs(v.x); p[1] = f2bs(v.y); p[2] = f2bs(v.z); p[3] = f2bs(v.w);
            *(s16x4*)&o2[(size_t)j * 4] = p;
        }
    } else if (B < 2048) {
        const int idx = B - 1024;
        const int bs = idx & 15, bc = (idx >> 4) & 7, b = idx >> 7;
        __shared__ short T[64][72];
        {
            const int cl = tid >> 4;
            const int s4 = (tid & 15) * 4;
            #pragma unroll
            for (int r = 0; r < 4; ++r) {
                const int c = cl + 16 * r;
                float4 v = *(const float4*)&x[((size_t)b * CC + bc * 64 + c) * SB + bs * 64 + s4];
                T[s4 + 0][c] = f2bs(v.x); T[s4 + 1][c] = f2bs(v.y);
                T[s4 + 2][c] = f2bs(v.z); T[s4 + 3][c] = f2bs(v.w);
            }
        }
        __syncthreads();
        {
            const int sl = tid >> 2;
            const int c16 = (tid & 3) * 16;
            short8 v0 = *(const short8*)&T[sl][c16];
            short8 v1 = *(const short8*)&T[sl][c16 + 8];
            short* dst = &xT[((size_t)b * SB + bs * 64 + sl) * CC + bc * 64 + c16];
            *(short8*)&dst[0] = v0;
            *(short8*)&dst[8] = v1;
        }
    } else if (B < 2080) {
        const int gi = (B - 2048) * 256 + tid;
        if (gi < NB * SB) maskf[gi] = (mask[gi] != 0) ? -FLT_MAX : 0.f;
    } else {
        const int i = (B - 2080) * 256 + tid;
        if (i < NB * CC) vmean[i] = 0.f;
    }
}

// ---------------------------------------------------------------------------
// qkv GEMM (R15): 64(o) x 128(s) tile, grid (8,24,8) = 1536 blocks ->
// 6 blocks/CU = 24 waves/CU. LDS 24 KB. One head per o-tile for q/k.
// o<512 -> qT[b,h,s,d] * (0.125*log2e); o<1024 -> kT[b,h,s,d];
// else v[b,c,s] + fp32 atomic partial sums into vmean[b][c] (raw sums).
// ---------------------------------------------------------------------------
__global__ __launch_bounds__(256)
void gemm_qkv(const short* __restrict__ A, const float* __restrict__ bias,
              const short* __restrict__ BT,
              short* __restrict__ qTo, short* __restrict__ kTo,
              short* __restrict__ vo, float* __restrict__ vmean)
{
    const int bs = blockIdx.x;   // s-tile (8)
    const int bo = blockIdx.y;   // o-tile (24)
    const int b  = blockIdx.z;
    const int tid = threadIdx.x;
    const int wave = tid >> 6, lane = tid & 63, lg = lane >> 4, ln = lane & 15;
    const int wo = wave >> 1, ws = wave & 1;

    __shared__ short Al[64 * 64];    //  8 KB
    __shared__ short Bl[128 * 64];   // 16 KB

    f32x4 acc[2][4];
    #pragma unroll
    for (int mt = 0; mt < 2; ++mt)
        #pragma unroll
        for (int nt = 0; nt < 4; ++nt) acc[mt][nt] = (f32x4){0.f, 0.f, 0.f, 0.f};

    const char* Ab = (const char*)(A + (size_t)bo * 64 * 512);
    const char* Bb = (const char*)(BT + ((size_t)b * SB + bs * 128) * 512);

    for (int kc = 0; kc < 512; kc += 64) {
        __syncthreads();
        #pragma unroll
        for (int sw = 0; sw < 2; ++sw) {     // A: 8KB
            const int lin = tid * 16 + sw * 4096;
            const int row = lin >> 7;         // 0..63
            const int scol = (lin & 127) ^ ((row & 7) << 4);
            gload16(Ab + ((size_t)row * 512 + kc) * 2 + scol,
                    (char*)Al + (wave << 10) + (sw << 12));
        }
        #pragma unroll
        for (int sw = 0; sw < 4; ++sw) {     // B: 16KB
            const int lin = tid * 16 + sw * 4096;
            const int row = lin >> 7;         // 0..127
            const int scol = (lin & 127) ^ ((row & 7) << 4);
            gload16(Bb + ((size_t)row * 512 + kc) * 2 + scol,
                    (char*)Bl + (wave << 10) + (sw << 12));
        }
        __syncthreads();
        #pragma unroll
        for (int kk = 0; kk < 2; ++kk) {
            const int colb = kk * 64 + lg * 16;
            short8 a[2], bb[4];
            #pragma unroll
            for (int mt = 0; mt < 2; ++mt)
                a[mt] = *(const short8*)&Al[sidx(wo * 32 + mt * 16 + ln, colb)];
            #pragma unroll
            for (int nt = 0; nt < 4; ++nt)
                bb[nt] = *(const short8*)&Bl[sidx(ws * 64 + nt * 16 + ln, colb)];
            #pragma unroll
            for (int mt = 0; mt < 2; ++mt)
                #pragma unroll
                for (int nt = 0; nt < 4; ++nt)
                    acc[mt][nt] = __builtin_amdgcn_mfma_f32_16x16x32_bf16(
                        a[mt], bb[nt], acc[mt][nt], 0, 0, 0);
        }
    }

    if (bo < 16) {   // q or k -> transposed [b,h,s,d]; one head per block
        short* dst = (bo < 8) ? qTo : kTo;
        const int h = bo & 7;
        const float sc = (bo < 8) ? 0.18033688011112042f : 1.0f;  // 0.125*log2(e)
        #pragma unroll
        for (int mt = 0; mt < 2; ++mt) {
            const int d0 = wo * 32 + mt * 16 + 4 * lg;
            const int o0 = bo * 64 + d0;
            const float b0 = bias[o0], b1 = bias[o0 + 1],
                        b2 = bias[o0 + 2], b3 = bias[o0 + 3];
            #pragma unroll
            for (int nt = 0; nt < 4; ++nt) {
                const int s = bs * 128 + ws * 64 + nt * 16 + ln;
                s16x4 pk;
                pk[0] = f2bs((acc[mt][nt][0] + b0) * sc);
                pk[1] = f2bs((acc[mt][nt][1] + b1) * sc);
                pk[2] = f2bs((acc[mt][nt][2] + b2) * sc);
                pk[3] = f2bs((acc[mt][nt][3] + b3) * sc);
                *(s16x4*)&dst[(((size_t)b * NH + h) * SB + s) * HD + d0] = pk;
            }
        }
    } else {        // v -> natural [b,c,s] + vmean partial sums
        #pragma unroll
        for (int mt = 0; mt < 2; ++mt) {
            const int cv0 = (bo - 16) * 64 + wo * 32 + mt * 16 + 4 * lg;
            #pragma unroll
            for (int r = 0; r < 4; ++r) {
                const float bv = bias[1024 + cv0 + r];
                float part = 0.f;
                #pragma unroll
                for (int nt = 0; nt < 4; ++nt) {
                    const int s = bs * 128 + ws * 64 + nt * 16 + ln;
                    const float val = acc[mt][nt][r] + bv;
                    part += val;
                    vo[((size_t)b * CC + cv0 + r) * SB + s] = f2bs(val);
                }
                #pragma unroll
                for (int o = 1; o < 16; o <<= 1)
                    part += __shfl_xor(part, o, 64);
                if (ln == 0)
                    atomicAdd(&vmean[(size_t)b * CC + cv0 + r], part);
            }
        }
    }
}

// ---------------------------------------------------------------------------
// proj GEMM (R16): 64(o) x 64(s) tile, grid (16,8,8) = 1024 blocks ->
// 4 blocks/CU = 16 waves/CU. LDS 16 KB. fp32 out [b,o,s].
// ---------------------------------------------------------------------------
__global__ __launch_bounds__(256)
void gemm_proj(const short* __restrict__ A, const float* __restrict__ bias,
               const short* __restrict__ BT, float* __restrict__ fo)
{
    const int bs = blockIdx.x;   // s-tile (16)
    const int bo = blockIdx.y;   // o-tile (8)
    const int b  = blockIdx.z;
    const int tid = threadIdx.x;
    const int wave = tid >> 6, lane = tid & 63, lg = lane >> 4, ln = lane & 15;
    const int wo = wave >> 1, ws = wave & 1;

    __shared__ short Al[64 * 64];    //  8 KB
    __shared__ short Bl[64 * 64];    //  8 KB

    f32x4 acc[2][2];
    #pragma unroll
    for (int mt = 0; mt < 2; ++mt)
        #pragma unroll
        for (int nt = 0; nt < 2; ++nt) acc[mt][nt] = (f32x4){0.f, 0.f, 0.f, 0.f};

    const char* Ab = (const char*)(A + (size_t)bo * 64 * 512);
    const char* Bb = (const char*)(BT + ((size_t)b * SB + bs * 64) * 512);

    for (int kc = 0; kc < 512; kc += 64) {
        __syncthreads();
        #pragma unroll
        for (int sw = 0; sw < 2; ++sw) {
            const int lin = tid * 16 + sw * 4096;
            const int row = lin >> 7;         // 0..63
            const int scol = (lin & 127) ^ ((row & 7) << 4);
            gload16(Ab + ((size_t)row * 512 + kc) * 2 + scol,
                    (char*)Al + (wave << 10) + (sw << 12));
            gload16(Bb + ((size_t)row * 512 + kc) * 2 + scol,
                    (char*)Bl + (wave << 10) + (sw << 12));
        }
        __syncthreads();
        #pragma unroll
        for (int kk = 0; kk < 2; ++kk) {
            const int colb = kk * 64 + lg * 16;
            short8 a[2], bb[2];
            #pragma unroll
            for (int mt = 0; mt < 2; ++mt)
                a[mt] = *(const short8*)&Al[sidx(wo * 32 + mt * 16 + ln, colb)];
            #pragma unroll
            for (int nt = 0; nt < 2; ++nt)
                bb[nt] = *(const short8*)&Bl[sidx(ws * 32 + nt * 16 + ln, colb)];
            #pragma unroll
            for (int mt = 0; mt < 2; ++mt)
                #pragma unroll
                for (int nt = 0; nt < 2; ++nt)
                    acc[mt][nt] = __builtin_amdgcn_mfma_f32_16x16x32_bf16(
                        a[mt], bb[nt], acc[mt][nt], 0, 0, 0);
        }
    }

    #pragma unroll
    for (int mt = 0; mt < 2; ++mt) {
        #pragma unroll
        for (int r = 0; r < 4; ++r) {
            const int o = bo * 64 + wo * 32 + mt * 16 + 4 * lg + r;
            const float bv = bias[o];
            #pragma unroll
            for (int nt = 0; nt < 2; ++nt) {
                const int s = bs * 64 + ws * 32 + nt * 16 + ln;
                fo[((size_t)b * CC + o) * SB + s] = acc[mt][nt][r] + bv;
            }
        }
    }
}

// ---------------------------------------------------------------------------
// Double-buffered MFMA attention (R18 version — best measured, restored).
//  - K/V LDS double-buffer, one barrier/tile; swapped mfma(K,Q)/mfma(V,P)
//    owner-lane softmax + accumulator; speculative softmax with stale m_;
//    defer-max; cvt_pk bf16 packing; deferred l-reduce; setprio on MFMA
//    clusters; Ps zero-pad XOR swizzle; mask from global; exp2 domain;
//    vmean/1024 for fully-masked rows.
//  - NOTE (R19 lesson): do NOT move V to registers — +64 VGPR of live state
//    trips the compiler's 64-VGPR allocation cliff (R6/R7/R19) and
//    serializes the loop. LDS staging for V stays.
// ---------------------------------------------------------------------------
__global__ __launch_bounds__(256, 4)
void attn_mfma(const short* __restrict__ qT, const short* __restrict__ kT,
               const short* __restrict__ vN, const float* __restrict__ maskf,
               const float* __restrict__ vmean, short* __restrict__ ctxT)
{
    const int L  = blockIdx.x;
    const int qb = 15 - (L >> 6);         // heavy blocks first
    const int bh = L & 63;                // XCD = L%8 = h -> per-(b,h) L2 reuse
    const int b  = bh >> 3, h = bh & 7;
    const int tid = threadIdx.x;
    const int wave = tid >> 6;
    const int lane = tid & 63;
    const int lg = lane >> 4;
    const int ln = lane & 15;

    __shared__ short Ks[2][64 * 64];      // 16384 B
    __shared__ short Vs[2][64 * 64];      // 16384 B
    __shared__ short Ps[4][16 * 64];      //  8192 B

    const char*  kbh = (const char*)(kT + (((size_t)b * NH + h) * SB) * HD);
    const char*  vbh = (const char*)(vN + ((size_t)b * CC + h * HD) * SB);
    const float* mb  = maskf + (size_t)b * SB;

    short8 qa0, qa1;
    {
        const short* qrow = qT + (((size_t)b * NH + h) * SB + qb * 64 + wave * 16 + ln) * HD;
        qa0 = *(const short8*)&qrow[8 * lg];
        qa1 = *(const short8*)&qrow[32 + 8 * lg];
    }

    const int psw = (ln & 7) << 3;        // per-row Ps XOR constant

    float m_ = -FLT_MAX, l_ = 0.f;        // l_ is a PER-LANE partial
    f32x4 acc[4];
    #pragma unroll
    for (int nt = 0; nt < 4; ++nt) acc[nt] = (f32x4){0.f, 0.f, 0.f, 0.f};

    auto stage = [&](int tb, int bi) {
        #pragma unroll
        for (int sw = 0; sw < 2; ++sw) {
            const int lin = tid * 16 + sw * 4096;
            const int row = lin >> 7;
            const int scol = (lin & 127) ^ ((row & 7) << 4);
            gload16(kbh + (size_t)tb * 128 + row * 128 + scol,
                    (char*)&Ks[bi][0] + (wave << 10) + (sw << 12));
            gload16(vbh + (size_t)row * (SB * 2) + tb * 2 + scol,
                    (char*)&Vs[bi][0] + (wave << 10) + (sw << 12));
        }
    };

    int cur = 0;
    stage(0, 0);
    __syncthreads();

    for (int t = 0; t <= qb; ++t) {
        const int tb = t * 64;

        // ---- mask loads issued FIRST (latency hides under QK^T) ----
        float4 mf[4];
        #pragma unroll
        for (int nt = 0; nt < 4; ++nt)
            mf[nt] = *(const float4*)&mb[tb + 16 * nt + 4 * lg];

        if (t < qb) stage((t + 1) * 64, cur ^ 1);

        // ---- swapped QK^T: sc[nt][r] = S[q=ln][key 16nt+4lg+r] ----
        f32x4 sc[4];
        __builtin_amdgcn_s_setprio(1);
        #pragma unroll
        for (int nt = 0; nt < 4; ++nt) {
            short8 kb0 = *(const short8*)&Ks[cur][sidx(ln + 16 * nt, lg * 16)];
            short8 kb1 = *(const short8*)&Ks[cur][sidx(ln + 16 * nt, 64 + lg * 16)];
            f32x4 z = (f32x4){0.f, 0.f, 0.f, 0.f};
            z = __builtin_amdgcn_mfma_f32_16x16x32_bf16(kb0, qa0, z, 0, 0, 0);
            z = __builtin_amdgcn_mfma_f32_16x16x32_bf16(kb1, qa1, z, 0, 0, 0);
            sc[nt] = z;
        }
        __builtin_amdgcn_s_setprio(0);

        #pragma unroll
        for (int nt = 0; nt < 4; ++nt) {
            sc[nt][0] += mf[nt].x; sc[nt][1] += mf[nt].y;
            sc[nt][2] += mf[nt].z; sc[nt][3] += mf[nt].w;
        }
        if (t == qb) {
            const int so = wave * 16 + ln;
            #pragma unroll
            for (int nt = 0; nt < 4; ++nt)
                #pragma unroll
                for (int r = 0; r < 4; ++r)
                    if (16 * nt + 4 * lg + r > so) sc[nt][r] = -FLT_MAX;
        }

        // ---- owner-lane in-register max, cross-lane reduce in flight ----
        float mx = sc[0][0];
        #pragma unroll
        for (int nt = 0; nt < 4; ++nt)
            #pragma unroll
            for (int r = 0; r < 4; ++r)
                if (nt | r) mx = fmaxf(mx, sc[nt][r]);
        float mxr = fmaxf(mx, __shfl_xor(mx, 16, 64));
        mxr = fmaxf(mxr, __shfl_xor(mxr, 32, 64));

        // ---- speculative P with STALE m_ (overlaps the shuffles) ----
        float rs = 0.f;
        int2 pkw[4];
        #pragma unroll
        for (int nt = 0; nt < 4; ++nt) {
            float p0 = exp2f(sc[nt][0] - m_);
            float p1 = exp2f(sc[nt][1] - m_);
            float p2 = exp2f(sc[nt][2] - m_);
            float p3 = exp2f(sc[nt][3] - m_);
            rs += (p0 + p1) + (p2 + p3);
            pkw[nt].x = cvtpk(p0, p1);
            pkw[nt].y = cvtpk(p2, p3);
        }

        // ---- rare path: some query's max grew beyond threshold ----
        if (!__all(mxr <= m_ + 11.5f)) {
            const float mnew = fmaxf(m_, mxr);
            const float fq = exp2f(m_ - mnew);   // 0-0 -> 1 (all-masked rows)
            l_ *= fq;
            #pragma unroll
            for (int nt = 0; nt < 4; ++nt)
                #pragma unroll
                for (int r = 0; r < 4; ++r) acc[nt][r] *= fq;
            m_ = mnew;
            rs = 0.f;
            #pragma unroll
            for (int nt = 0; nt < 4; ++nt) {
                float p0 = exp2f(sc[nt][0] - m_);
                float p1 = exp2f(sc[nt][1] - m_);
                float p2 = exp2f(sc[nt][2] - m_);
                float p3 = exp2f(sc[nt][3] - m_);
                rs += (p0 + p1) + (p2 + p3);
                pkw[nt].x = cvtpk(p0, p1);
                pkw[nt].y = cvtpk(p2, p3);
            }
        }

        // ---- commit P; l_ stays a per-lane partial (merged in epilogue) ----
        #pragma unroll
        for (int nt = 0; nt < 4; ++nt)
            *(int2*)&Ps[wave][ln * 64 + ((16 * nt + 4 * lg) ^ psw)] = pkw[nt];
        l_ += rs;

        // ---- PV as mfma(V, P): output cols = queries (own lane) ----
        const short8 pa0 = *(const short8*)&Ps[wave][ln * 64 + ((8 * lg) ^ psw)];
        const short8 pa1 = *(const short8*)&Ps[wave][ln * 64 + ((32 + 8 * lg) ^ psw)];
        __builtin_amdgcn_s_setprio(1);
        #pragma unroll
        for (int nt = 0; nt < 4; ++nt) {
            short8 va0 = *(const short8*)&Vs[cur][sidx(16 * nt + ln, lg * 16)];
            short8 va1 = *(const short8*)&Vs[cur][sidx(16 * nt + ln, 64 + lg * 16)];
            acc[nt] = __builtin_amdgcn_mfma_f32_16x16x32_bf16(va0, pa0, acc[nt], 0, 0, 0);
            acc[nt] = __builtin_amdgcn_mfma_f32_16x16x32_bf16(va1, pa1, acc[nt], 0, 0, 0);
        }
        __builtin_amdgcn_s_setprio(0);

        if (t < qb) {
            __syncthreads();
            cur ^= 1;
        }
    }

    // ---- epilogue: merge per-lane l partials (2 shfl), normalize, store ----
    float lt = l_ + __shfl_xor(l_, 16, 64);
    lt += __shfl_xor(lt, 32, 64);
    const float rl = 1.f / lt;
    const bool dead = (m_ == -FLT_MAX);
    const float* vmb = vmean + (size_t)b * CC + h * HD;
    const int s = qb * 64 + wave * 16 + ln;
    short* crow = ctxT + ((size_t)b * SB + s) * CC + h * HD;
    #pragma unroll
    for (int nt = 0; nt < 4; ++nt) {
        const int d0 = 16 * nt + 4 * lg;
        const float4 vm4 = *(const float4*)&vmb[d0];
        const float v0 = dead ? vm4.x * (1.f / 1024.f) : acc[nt][0] * rl;
        const float v1 = dead ? vm4.y * (1.f / 1024.f) : acc[nt][1] * rl;
        const float v2 = dead ? vm4.z * (1.f / 1024.f) : acc[nt][2] * rl;
        const float v3 = dead ? vm4.w * (1.f / 1024.f) : acc[nt][3] * rl;
        int2 w;
        w.x = cvtpk(v0, v1);
        w.y = cvtpk(v2, v3);
        *(int2*)&crow[d0] = w;
    }
}

extern "C" void kernel_launch(void* const* d_in, const int* in_sizes, int n_in,
                              void* d_out, int out_size, void* d_ws, size_t ws_size,
                              hipStream_t stream) {
    const float* x      = (const float*)d_in[0];
    const int*   amask  = (const int*)d_in[1];
    const float* qkv_w  = (const float*)d_in[2];
    const float* qkv_b  = (const float*)d_in[3];
    const float* proj_w = (const float*)d_in[4];
    const float* proj_b = (const float*)d_in[5];
    float* out = (float*)d_out;

    short* xT    = (short*)d_ws;                       // (B,S,C)
    short* w1b   = xT  + (size_t)NB * SB * CC;         // (1536,512)
    short* w2b   = w1b + (size_t)1536 * 512;           // (512,512)
    short* qT    = w2b + (size_t)512 * 512;            // (B,H,S,D)
    short* kT    = qT  + (size_t)NB * NH * SB * HD;    // (B,H,S,D)
    short* vN    = kT  + (size_t)NB * NH * SB * HD;    // (B,C,S)
    short* ctxT  = vN  + (size_t)NB * CC * SB;         // (B,S,C)
    float* vmean = (float*)(ctxT + (size_t)NB * SB * CC);  // (B,C) raw sums
    float* maskf = vmean + (size_t)NB * CC;            // (B,S)

    prep<<<2096, 256, 0, stream>>>(qkv_w, proj_w, w1b, w2b, x, xT,
                                   amask, maskf, vmean);
    gemm_qkv<<<dim3(8, 24, NB), 256, 0, stream>>>(
        w1b, qkv_b, xT, qT, kT, vN, vmean);
    attn_mfma<<<dim3(1024, 1, 1), 256, 0, stream>>>(qT, kT, vN, maskf, vmean, ctxT);
    gemm_proj<<<dim3(16, 8, NB), 256, 0, stream>>>(
        w2b, proj_b, ctxT, out);
}